// Round 1
// baseline (318.523 us; speedup 1.0000x reference)
//
#include <hip/hip_runtime.h>
#include <hip/hip_bf16.h>

#define N_TOK 65536
#define KCB   512
#define DIM   64

// Kernel 1: one thread per token. Codebook rows read wave-uniformly (scalar
// path), embedding held in VGPRs, 4-way split accumulators. Writes only the
// argmin index (as float) into the third output section.
__global__ __launch_bounds__(256) void vq_argmin_kernel(
    const float* __restrict__ cb,
    const float* __restrict__ emb,
    float* __restrict__ out) {
  __shared__ float csq[KCB];
  const int tid = threadIdx.x;

  // Per-block c_sq precompute (512 rows / 256 threads = 2 each); uniform-ish,
  // trivial cost vs the 32K-FMA main loop.
  for (int k = tid; k < KCB; k += 256) {
    const float* row = cb + k * DIM;
    float s = 0.f;
#pragma unroll
    for (int d = 0; d < DIM; ++d) s = fmaf(row[d], row[d], s);
    csq[k] = s;
  }
  __syncthreads();

  const int t = blockIdx.x * 256 + tid;

  // Load the token's 64 floats into registers (16x float4, coalesced).
  float e[DIM];
  const float4* ep = reinterpret_cast<const float4*>(emb + (size_t)t * DIM);
#pragma unroll
  for (int i = 0; i < DIM / 4; ++i) {
    float4 v = ep[i];
    e[4 * i + 0] = v.x;
    e[4 * i + 1] = v.y;
    e[4 * i + 2] = v.z;
    e[4 * i + 3] = v.w;
  }

  float best = 3.4e38f;
  int bidx = 0;

#pragma unroll 2
  for (int k = 0; k < KCB; ++k) {
    const float* row = cb + k * DIM;  // wave-uniform address -> s_load
    float s0 = 0.f, s1 = 0.f, s2 = 0.f, s3 = 0.f;
#pragma unroll
    for (int d = 0; d < DIM; d += 4) {
      s0 = fmaf(row[d + 0], e[d + 0], s0);
      s1 = fmaf(row[d + 1], e[d + 1], s1);
      s2 = fmaf(row[d + 2], e[d + 2], s2);
      s3 = fmaf(row[d + 3], e[d + 3], s3);
    }
    const float dot = (s0 + s1) + (s2 + s3);
    const float score = fmaf(-2.f, dot, csq[k]);
    if (score < best) {
      best = score;
      bidx = k;
    }
  }

  // index section starts at 2*N*D
  out[(size_t)2 * N_TOK * DIM + t] = (float)bidx;
}

// Kernel 2: coalesced gather-write of the two quantized sections.
// 16 lanes per token, one float4 each; wave covers 4 tokens contiguously.
__global__ __launch_bounds__(256) void vq_gather_kernel(
    const float* __restrict__ cb,
    float* __restrict__ out) {
  const int gid = blockIdx.x * 256 + threadIdx.x;  // 0 .. N_TOK*16-1
  const int t = gid >> 4;
  const int j = gid & 15;

  const int idx = (int)out[(size_t)2 * N_TOK * DIM + t];

  const float4* cb4 = reinterpret_cast<const float4*>(cb);
  float4* out4 = reinterpret_cast<float4*>(out);

  const float4 v = cb4[idx * (DIM / 4) + j];
  out4[(size_t)t * (DIM / 4) + j] = v;                          // quantized_codebook
  out4[(size_t)N_TOK * (DIM / 4) + (size_t)t * (DIM / 4) + j] = v;  // straight_through
}

extern "C" void kernel_launch(void* const* d_in, const int* in_sizes, int n_in,
                              void* d_out, int out_size, void* d_ws, size_t ws_size,
                              hipStream_t stream) {
  const float* cb  = (const float*)d_in[0];   // (512, 64) f32
  const float* emb = (const float*)d_in[1];   // (65536, 1, 64) f32
  float* out = (float*)d_out;                 // [2*N*D quantized | N index] f32

  vq_argmin_kernel<<<N_TOK / 256, 256, 0, stream>>>(cb, emb, out);
  vq_gather_kernel<<<(N_TOK * 16) / 256, 256, 0, stream>>>(cb, out);
}

// Round 2
// 93.240 us; speedup vs baseline: 3.4162x; 3.4162x over previous
//
#include <hip/hip_runtime.h>
#include <hip/hip_bf16.h>

#define N_TOK 65536
#define KCB   512
#define DIM   64
#define KSLICES 4   // waves per block, each covers KCB/KSLICES codebook rows

// Block = 256 threads = 4 waves; handles 64 tokens (one per lane).
// Wave w scores codebook rows [w*128, w*128+128) for its lane's token.
// Cross-wave argmin merge in LDS. Token held in VGPRs (16x float4).
__global__ __launch_bounds__(256, 4) void vq_argmin_kernel(
    const float* __restrict__ cb,
    const float* __restrict__ emb,
    float* __restrict__ out) {
  __shared__ float csq[KCB];
  __shared__ float rbest[KSLICES][64];
  __shared__ int   ridx[KSLICES][64];

  const int tid  = threadIdx.x;
  const int lane = tid & 63;
  const int wave = tid >> 6;
  const int t    = blockIdx.x * 64 + lane;

  // c_sq precompute: 512 rows / 256 threads = 2 rows each.
  for (int k = tid; k < KCB; k += 256) {
    const float4* row4 = reinterpret_cast<const float4*>(cb + (size_t)k * DIM);
    float s = 0.f;
#pragma unroll
    for (int i = 0; i < DIM / 4; ++i) {
      float4 c = row4[i];
      s += c.x * c.x + c.y * c.y + c.z * c.z + c.w * c.w;
    }
    csq[k] = s;
  }

  // Token into registers: 16 x float4 = 64 VGPRs.
  float4 ev[DIM / 4];
  const float4* ep = reinterpret_cast<const float4*>(emb + (size_t)t * DIM);
#pragma unroll
  for (int i = 0; i < DIM / 4; ++i) ev[i] = ep[i];

  __syncthreads();

  // Wave-uniform slice base -> scalar-path codebook loads.
  const int kbase = __builtin_amdgcn_readfirstlane(wave * (KCB / KSLICES));

  float best = 3.4e38f;
  int bidx = kbase;

#pragma unroll 2
  for (int kk = 0; kk < KCB / KSLICES; ++kk) {
    const int k = kbase + kk;
    const float4* row4 = reinterpret_cast<const float4*>(cb + (size_t)k * DIM);
    float s0 = 0.f, s1 = 0.f, s2 = 0.f, s3 = 0.f;
#pragma unroll
    for (int i = 0; i < DIM / 4; ++i) {
      float4 c = row4[i];
      s0 = fmaf(c.x, ev[i].x, s0);
      s1 = fmaf(c.y, ev[i].y, s1);
      s2 = fmaf(c.z, ev[i].z, s2);
      s3 = fmaf(c.w, ev[i].w, s3);
    }
    const float dot = (s0 + s1) + (s2 + s3);
    const float score = fmaf(-2.f, dot, csq[k]);
    if (score < best) {   // strict < keeps lowest index within slice
      best = score;
      bidx = k;
    }
  }

  rbest[wave][lane] = best;
  ridx[wave][lane] = bidx;
  __syncthreads();

  if (tid < 64) {  // wave 0 merges in ascending-slice order (lowest-index ties)
    float b = rbest[0][lane];
    int bi = ridx[0][lane];
#pragma unroll
    for (int w = 1; w < KSLICES; ++w) {
      float ob = rbest[w][lane];
      int oi = ridx[w][lane];
      if (ob < b) { b = ob; bi = oi; }
    }
    out[(size_t)2 * N_TOK * DIM + blockIdx.x * 64 + lane] = (float)bi;
  }
}

// Gather-write of the two quantized sections. 16 lanes per token, one float4
// each; wave covers 4 tokens contiguously -> fully coalesced stores.
__global__ __launch_bounds__(256) void vq_gather_kernel(
    const float* __restrict__ cb,
    float* __restrict__ out) {
  const int gid = blockIdx.x * 256 + threadIdx.x;  // 0 .. N_TOK*16-1
  const int t = gid >> 4;
  const int j = gid & 15;

  const int idx = (int)out[(size_t)2 * N_TOK * DIM + t];

  const float4* cb4 = reinterpret_cast<const float4*>(cb);
  float4* out4 = reinterpret_cast<float4*>(out);

  const float4 v = cb4[idx * (DIM / 4) + j];
  out4[(size_t)t * (DIM / 4) + j] = v;                               // quantized_codebook
  out4[(size_t)N_TOK * (DIM / 4) + (size_t)t * (DIM / 4) + j] = v;   // straight_through
}

extern "C" void kernel_launch(void* const* d_in, const int* in_sizes, int n_in,
                              void* d_out, int out_size, void* d_ws, size_t ws_size,
                              hipStream_t stream) {
  const float* cb  = (const float*)d_in[0];   // (512, 64) f32
  const float* emb = (const float*)d_in[1];   // (65536, 1, 64) f32
  float* out = (float*)d_out;                 // [2*N*D quantized | N index] f32

  vq_argmin_kernel<<<N_TOK / 64, 256, 0, stream>>>(cb, emb, out);
  vq_gather_kernel<<<(N_TOK * 16) / 256, 256, 0, stream>>>(cb, out);
}

// Round 3
// 93.061 us; speedup vs baseline: 3.4227x; 1.0019x over previous
//
#include <hip/hip_runtime.h>
#include <hip/hip_bf16.h>

#define N_TOK 65536
#define KCB   512
#define DIM   64
#define KSLICES 4   // waves per block, each covers KCB/KSLICES codebook rows

// Block = 256 threads = 4 waves; handles 64 tokens (one per lane).
// Wave w scores codebook rows [w*128, w*128+128) for its lane's token.
// Cross-wave argmin merge in LDS. Token held in VGPRs (16x float4),
// pinned there with an opaque asm barrier so the compiler cannot sink
// the loads into the k-loop (round-2 failure: VGPR=48, FETCH=8.7GB).
__global__ __launch_bounds__(256, 4) void vq_argmin_kernel(
    const float* __restrict__ cb,
    const float* __restrict__ emb,
    float* __restrict__ out) {
  __shared__ float csq[KCB];
  __shared__ float rbest[KSLICES][64];
  __shared__ int   ridx[KSLICES][64];

  const int tid  = threadIdx.x;
  const int lane = tid & 63;
  const int wave = tid >> 6;
  const int t    = blockIdx.x * 64 + lane;

  // c_sq precompute: 512 rows / 256 threads = 2 rows each.
  for (int k = tid; k < KCB; k += 256) {
    const float4* row4 = reinterpret_cast<const float4*>(cb + (size_t)k * DIM);
    float s = 0.f;
#pragma unroll
    for (int i = 0; i < DIM / 4; ++i) {
      float4 c = row4[i];
      s += c.x * c.x + c.y * c.y + c.z * c.z + c.w * c.w;
    }
    csq[k] = s;
  }

  // Token into registers: 16 x float4 = 64 VGPRs.
  float4 ev[DIM / 4];
  const float4* ep = reinterpret_cast<const float4*>(emb + (size_t)t * DIM);
#pragma unroll
  for (int i = 0; i < DIM / 4; ++i) ev[i] = ep[i];

  // Pin ev in VGPRs: opaque to the optimizer -> cannot rematerialize the
  // global loads inside the loop, must keep all 64 floats live.
#pragma unroll
  for (int i = 0; i < DIM / 4; ++i) {
    asm volatile("" : "+v"(ev[i].x), "+v"(ev[i].y), "+v"(ev[i].z), "+v"(ev[i].w));
  }

  __syncthreads();

  // Wave-uniform slice base -> scalar-path codebook loads.
  const int kbase = __builtin_amdgcn_readfirstlane(wave * (KCB / KSLICES));

  float best = 3.4e38f;
  int bidx = kbase;

#pragma unroll 2
  for (int kk = 0; kk < KCB / KSLICES; ++kk) {
    const int k = kbase + kk;
    const float4* row4 = reinterpret_cast<const float4*>(cb + (size_t)k * DIM);
    float s0 = 0.f, s1 = 0.f, s2 = 0.f, s3 = 0.f;
#pragma unroll
    for (int i = 0; i < DIM / 4; ++i) {
      float4 c = row4[i];
      s0 = fmaf(c.x, ev[i].x, s0);
      s1 = fmaf(c.y, ev[i].y, s1);
      s2 = fmaf(c.z, ev[i].z, s2);
      s3 = fmaf(c.w, ev[i].w, s3);
    }
    const float dot = (s0 + s1) + (s2 + s3);
    const float score = fmaf(-2.f, dot, csq[k]);
    if (score < best) {   // strict < keeps lowest index within slice
      best = score;
      bidx = k;
    }
  }

  rbest[wave][lane] = best;
  ridx[wave][lane] = bidx;
  __syncthreads();

  if (tid < 64) {  // wave 0 merges in ascending-slice order (lowest-index ties)
    float b = rbest[0][lane];
    int bi = ridx[0][lane];
#pragma unroll
    for (int w = 1; w < KSLICES; ++w) {
      float ob = rbest[w][lane];
      int oi = ridx[w][lane];
      if (ob < b) { b = ob; bi = oi; }
    }
    out[(size_t)2 * N_TOK * DIM + blockIdx.x * 64 + lane] = (float)bi;
  }
}

// Gather-write of the two quantized sections. 16 lanes per token, one float4
// each; wave covers 4 tokens contiguously -> fully coalesced stores.
__global__ __launch_bounds__(256) void vq_gather_kernel(
    const float* __restrict__ cb,
    float* __restrict__ out) {
  const int gid = blockIdx.x * 256 + threadIdx.x;  // 0 .. N_TOK*16-1
  const int t = gid >> 4;
  const int j = gid & 15;

  const int idx = (int)out[(size_t)2 * N_TOK * DIM + t];

  const float4* cb4 = reinterpret_cast<const float4*>(cb);
  float4* out4 = reinterpret_cast<float4*>(out);

  const float4 v = cb4[idx * (DIM / 4) + j];
  out4[(size_t)t * (DIM / 4) + j] = v;                               // quantized_codebook
  out4[(size_t)N_TOK * (DIM / 4) + (size_t)t * (DIM / 4) + j] = v;   // straight_through
}

extern "C" void kernel_launch(void* const* d_in, const int* in_sizes, int n_in,
                              void* d_out, int out_size, void* d_ws, size_t ws_size,
                              hipStream_t stream) {
  const float* cb  = (const float*)d_in[0];   // (512, 64) f32
  const float* emb = (const float*)d_in[1];   // (65536, 1, 64) f32
  float* out = (float*)d_out;                 // [2*N*D quantized | N index] f32

  vq_argmin_kernel<<<N_TOK / 64, 256, 0, stream>>>(cb, emb, out);
  vq_gather_kernel<<<(N_TOK * 16) / 256, 256, 0, stream>>>(cb, out);
}

// Round 4
// 83.903 us; speedup vs baseline: 3.7963x; 1.1091x over previous
//
#include <hip/hip_runtime.h>
#include <hip/hip_bf16.h>

#define N_TOK 65536
#define KCB   512
#define DIM   64
#define TOK_BLK   64    // tokens per block
#define ROW_CHUNK 128   // codebook rows per LDS chunk
#define NCHUNK    (KCB / ROW_CHUNK)  // 4
#define TT 4            // tokens per thread (16 token-groups)
#define TR 8            // rows per thread  (16 row-groups)

// Bijective slot swizzle: at fixed g, the 16 tokens (or rows) a wave touches
// map to 16 distinct 16B slots -> conflict-free ds_read_b128.
// (T + (T>>2)) & 15 is a bijection of T mod 16 AND spreads T-values that
// differ by multiples of 4 (our wave layout) across all 16 slots.
__device__ __forceinline__ int sw16(int T) { return (T + (T >> 2)) & 15; }

// Monotone map: f32 bits -> u32 such that u-compare == f32 compare (total order).
__device__ __forceinline__ unsigned mono(float f) {
  unsigned u = __float_as_uint(f);
  return u ^ ((unsigned)(-(int)(u >> 31)) | 0x80000000u);
}

// Tiny one-shot kernel: csq[k] = sum(cb[k]^2) into workspace.
__global__ __launch_bounds__(256) void vq_csq_kernel(
    const float* __restrict__ cb, float* __restrict__ csq) {
  const int k = blockIdx.x * 256 + threadIdx.x;
  if (k >= KCB) return;
  const float4* row4 = reinterpret_cast<const float4*>(cb + (size_t)k * DIM);
  float s = 0.f;
#pragma unroll
  for (int i = 0; i < DIM / 4; ++i) {
    float4 c = row4[i];
    s = fmaf(c.x, c.x, s);
    s = fmaf(c.y, c.y, s);
    s = fmaf(c.z, c.z, s);
    s = fmaf(c.w, c.w, s);
  }
  csq[k] = s;
}

// Register-tiled GEMM + fused argmin.
// Block: 256 threads = 16 token-groups x 16 row-groups.
// Thread tile: TT=4 tokens x TR=8 rows. LDS: tokens 16KB + cb chunk 32KB.
__global__ __launch_bounds__(256, 3) void vq_argmin_kernel(
    const float* __restrict__ cb,
    const float* __restrict__ emb,
    const float* __restrict__ csqg,
    float* __restrict__ out) {
  __shared__ float4 et4[TOK_BLK * 16];     // 16 KB, swizzled [token][slot]
  __shared__ float4 cbs[ROW_CHUNK * 16];   // 32 KB, swizzled [row][slot]

  const int tid = threadIdx.x;
  const int tg  = tid & 15;   // token group: tokens 4tg..4tg+3
  const int rg  = tid >> 4;   // row group:   rows  8rg..8rg+7 (per chunk)
  const int tok0 = blockIdx.x * TOK_BLK;

  const float4* emb4 = reinterpret_cast<const float4*>(emb);
  const float4* cbg4 = reinterpret_cast<const float4*>(cb);

  // ---- stage token tile (64 x 16 float4), swizzled, fully coalesced ----
#pragma unroll
  for (int m = 0; m < (TOK_BLK * 16) / 256; ++m) {
    const int i = tid + 256 * m;
    const int T = i >> 4, s = i & 15;
    *reinterpret_cast<float4*>(
        reinterpret_cast<char*>(et4) + (((unsigned)T << 8) ^ ((unsigned)(s ^ sw16(T)) << 4))) =
        emb4[(size_t)(tok0 + T) * 16 + s];
  }

  // Per-thread XOR-folded byte bases: addr = basex ^ (g<<4).
  unsigned bx_t[TT], bx_r[TR];
#pragma unroll
  for (int j = 0; j < TT; ++j) {
    const int T = 4 * tg + j;
    bx_t[j] = ((unsigned)T << 8) ^ ((unsigned)sw16(T) << 4);
  }

  unsigned long long best[TT];
#pragma unroll
  for (int j = 0; j < TT; ++j) best[j] = ~0ull;

  for (int c = 0; c < NCHUNK; ++c) {
    const int kbase = c * ROW_CHUNK;
    if (c) __syncthreads();  // previous chunk's reads complete

    // ---- stage codebook chunk (128 x 16 float4), swizzled, coalesced ----
#pragma unroll
    for (int m = 0; m < (ROW_CHUNK * 16) / 256; ++m) {
      const int i = tid + 256 * m;
      const int R = i >> 4, s = i & 15;
      *reinterpret_cast<float4*>(
          reinterpret_cast<char*>(cbs) + (((unsigned)R << 8) ^ ((unsigned)(s ^ sw16(R)) << 4))) =
          cbg4[(size_t)(kbase + R) * 16 + s];
    }
    __syncthreads();

#pragma unroll
    for (int i = 0; i < TR; ++i) {
      const int R = 8 * rg + i;
      bx_r[i] = ((unsigned)R << 8) ^ ((unsigned)sw16(R) << 4);
    }

    float acc[TT][TR];
#pragma unroll
    for (int j = 0; j < TT; ++j)
#pragma unroll
      for (int i = 0; i < TR; ++i) acc[j][i] = 0.f;

    // ---- inner GEMM: 16 d-groups of 4; 12 ds_read_b128 : 128 fmac ----
#pragma unroll 4
    for (int g = 0; g < 16; ++g) {
      const unsigned g16 = (unsigned)g << 4;
      float4 tf[TT], rf[TR];
#pragma unroll
      for (int j = 0; j < TT; ++j)
        tf[j] = *reinterpret_cast<const float4*>(reinterpret_cast<const char*>(et4) + (bx_t[j] ^ g16));
#pragma unroll
      for (int i = 0; i < TR; ++i)
        rf[i] = *reinterpret_cast<const float4*>(reinterpret_cast<const char*>(cbs) + (bx_r[i] ^ g16));
#pragma unroll
      for (int j = 0; j < TT; ++j)
#pragma unroll
        for (int i = 0; i < TR; ++i) {
          acc[j][i] = fmaf(tf[j].x, rf[i].x, acc[j][i]);
          acc[j][i] = fmaf(tf[j].y, rf[i].y, acc[j][i]);
          acc[j][i] = fmaf(tf[j].z, rf[i].z, acc[j][i]);
          acc[j][i] = fmaf(tf[j].w, rf[i].w, acc[j][i]);
        }
    }

    // ---- fold scores into per-token (score,idx) packed u64 ----
#pragma unroll
    for (int i = 0; i < TR; ++i) {
      const int k = kbase + 8 * rg + i;
      const float cs = csqg[k];
#pragma unroll
      for (int j = 0; j < TT; ++j) {
        const float score = fmaf(-2.f, acc[j][i], cs);
        const unsigned long long p = ((unsigned long long)mono(score) << 32) | (unsigned)k;
        best[j] = p < best[j] ? p : best[j];
      }
    }
  }

  // ---- cross-thread argmin reduce (alias cbs as u64 red[16][64]) ----
  __syncthreads();
  unsigned long long* red = reinterpret_cast<unsigned long long*>(cbs);
#pragma unroll
  for (int j = 0; j < TT; ++j) red[rg * TOK_BLK + 4 * tg + j] = best[j];
  __syncthreads();

  if (tid < TOK_BLK) {
    unsigned long long b = red[tid];
#pragma unroll
    for (int r = 1; r < 16; ++r) {
      unsigned long long o = red[r * TOK_BLK + tid];
      b = o < b ? o : b;
    }
    out[(size_t)2 * N_TOK * DIM + tok0 + tid] = (float)(unsigned)(b & 0xFFFFFFFFull);
  }
}

// Gather-write of the two quantized sections. 16 lanes per token, one float4
// each; fully coalesced stores; codebook (128 KB) is L2-resident.
__global__ __launch_bounds__(256) void vq_gather_kernel(
    const float* __restrict__ cb,
    float* __restrict__ out) {
  const int gid = blockIdx.x * 256 + threadIdx.x;  // 0 .. N_TOK*16-1
  const int t = gid >> 4;
  const int j = gid & 15;

  const int idx = (int)out[(size_t)2 * N_TOK * DIM + t];

  const float4* cb4 = reinterpret_cast<const float4*>(cb);
  float4* out4 = reinterpret_cast<float4*>(out);

  const float4 v = cb4[idx * (DIM / 4) + j];
  out4[(size_t)t * (DIM / 4) + j] = v;                               // quantized_codebook
  out4[(size_t)N_TOK * (DIM / 4) + (size_t)t * (DIM / 4) + j] = v;   // straight_through
}

extern "C" void kernel_launch(void* const* d_in, const int* in_sizes, int n_in,
                              void* d_out, int out_size, void* d_ws, size_t ws_size,
                              hipStream_t stream) {
  const float* cb  = (const float*)d_in[0];   // (512, 64) f32
  const float* emb = (const float*)d_in[1];   // (65536, 1, 64) f32
  float* out = (float*)d_out;                 // [2*N*D quantized | N index] f32
  float* csq = (float*)d_ws;                  // 512 floats scratch

  vq_csq_kernel<<<KCB / 256, 256, 0, stream>>>(cb, csq);
  vq_argmin_kernel<<<N_TOK / TOK_BLK, 256, 0, stream>>>(cb, emb, csq, out);
  vq_gather_kernel<<<(N_TOK * 16) / 256, 256, 0, stream>>>(cb, out);
}